// Round 1
// baseline (4244.788 us; speedup 1.0000x reference)
//
#include <hip/hip_runtime.h>
#include <hip/hip_bf16.h>
#include <math.h>

// Dense fp32 baseline for the 3-stage early-exit MLP cascade.
// Stages 1-2 must be fp32-accurate: exit masks compare max-softmax-prob vs
// 0.01 and the distribution is centered right at the threshold; low-precision
// backbones flip masks -> O(3) absmax errors. See session notes.

#define BM 128
#define BN 128
#define BK 16

__global__ __launch_bounds__(256) void gemm_bias_act(
    const float* __restrict__ A, const float* __restrict__ B,
    const float* __restrict__ bias, float* __restrict__ C,
    int M, int N, int K, int do_relu)
{
    // A: [M,K] row-major, B: [K,N] row-major, C: [M,N] row-major.
    // M % 128 == 0 and K % 16 == 0 assumed (true for all 6 GEMMs here).
    __shared__ float As[BK][BM + 4];   // transposed: As[k][m]; +4 keeps 16B align
    __shared__ float Bs[BK][BN + 4];

    const int tid = threadIdx.x;
    const int tx = tid & 15;           // column group (0..15)
    const int ty = tid >> 4;           // row group (0..15)
    const int m0 = blockIdx.y * BM;
    const int n0 = blockIdx.x * BN;

    float acc[8][8];
    #pragma unroll
    for (int i = 0; i < 8; ++i)
        #pragma unroll
        for (int j = 0; j < 8; ++j) acc[i][j] = 0.f;

    for (int k0 = 0; k0 < K; k0 += BK) {
        // ---- stage A tile (BM x BK) -> LDS transposed ----
        #pragma unroll
        for (int i = 0; i < 2; ++i) {
            int s = tid + i * 256;               // 0..511 float4 slots
            int row = s >> 2;                    // 0..127
            int c4 = s & 3;                      // 0..3
            const float4 v = *(const float4*)(A + (size_t)(m0 + row) * K + k0 + c4 * 4);
            As[c4 * 4 + 0][row] = v.x;
            As[c4 * 4 + 1][row] = v.y;
            As[c4 * 4 + 2][row] = v.z;
            As[c4 * 4 + 3][row] = v.w;
        }
        // ---- stage B tile (BK x BN) -> LDS, guarded for N=1000 edge ----
        #pragma unroll
        for (int i = 0; i < 2; ++i) {
            int s = tid + i * 256;
            int kk = s >> 5;                     // 0..15
            int n4 = s & 31;                     // 0..31
            int col = n0 + n4 * 4;
            const float* src = B + (size_t)(k0 + kk) * N + col;
            float4 v;
            if (col + 3 < N) {
                v = *(const float4*)src;
            } else {
                v.x = (col + 0 < N) ? src[0] : 0.f;
                v.y = (col + 1 < N) ? src[1] : 0.f;
                v.z = (col + 2 < N) ? src[2] : 0.f;
                v.w = (col + 3 < N) ? src[3] : 0.f;
            }
            *(float4*)(&Bs[kk][n4 * 4]) = v;
        }
        __syncthreads();

        // ---- inner product: 8x8 micro-tile per thread ----
        #pragma unroll
        for (int k = 0; k < BK; ++k) {
            const float4 a0 = *(const float4*)(&As[k][ty * 8]);
            const float4 a1 = *(const float4*)(&As[k][ty * 8 + 4]);
            const float4 b0 = *(const float4*)(&Bs[k][tx * 8]);
            const float4 b1 = *(const float4*)(&Bs[k][tx * 8 + 4]);
            const float a[8]  = {a0.x, a0.y, a0.z, a0.w, a1.x, a1.y, a1.z, a1.w};
            const float bb[8] = {b0.x, b0.y, b0.z, b0.w, b1.x, b1.y, b1.z, b1.w};
            #pragma unroll
            for (int i = 0; i < 8; ++i)
                #pragma unroll
                for (int j = 0; j < 8; ++j)
                    acc[i][j] = fmaf(a[i], bb[j], acc[i][j]);
        }
        __syncthreads();
    }

    // ---- epilogue: bias (+ optional relu), guarded store ----
    #pragma unroll
    for (int i = 0; i < 8; ++i) {
        int row = m0 + ty * 8 + i;
        #pragma unroll
        for (int j = 0; j < 8; ++j) {
            int col = n0 + tx * 8 + j;
            if (col < N) {
                float v = acc[i][j] + bias[col];
                if (do_relu) v = fmaxf(v, 0.f);
                C[(size_t)row * N + col] = v;
            }
        }
    }
}

// Exit mask: max softmax prob > 0.01  <=>  sum(exp(l - max)) < 100
__global__ __launch_bounds__(256) void conf_kernel(
    const float* __restrict__ P, int N, int* __restrict__ cm)
{
    const int b = blockIdx.x;
    const float* row = P + (size_t)b * N;

    float m = -3.0e38f;
    for (int c = threadIdx.x; c < N; c += 256) m = fmaxf(m, row[c]);
    #pragma unroll
    for (int off = 32; off > 0; off >>= 1) m = fmaxf(m, __shfl_down(m, off));

    __shared__ float red_max[4];
    __shared__ float red_sum[4];
    const int wave = threadIdx.x >> 6;
    const int lane = threadIdx.x & 63;
    if (lane == 0) red_max[wave] = m;
    __syncthreads();
    m = fmaxf(fmaxf(red_max[0], red_max[1]), fmaxf(red_max[2], red_max[3]));

    float s = 0.f;
    for (int c = threadIdx.x; c < N; c += 256) s += expf(row[c] - m);
    #pragma unroll
    for (int off = 32; off > 0; off >>= 1) s += __shfl_down(s, off);
    if (lane == 0) red_sum[wave] = s;
    __syncthreads();
    if (threadIdx.x == 0) {
        float tot = red_sum[0] + red_sum[1] + red_sum[2] + red_sum[3];
        cm[b] = (tot < 100.0f) ? 1 : 0;
    }
}

// out currently holds p3; overwrite rows that exited earlier.
__global__ __launch_bounds__(256) void select_kernel(
    float* __restrict__ out, const float* __restrict__ p1,
    const float* __restrict__ p2, const int* __restrict__ c1,
    const int* __restrict__ c2, int N)
{
    const int b = blockIdx.y;
    const int c = blockIdx.x * 256 + threadIdx.x;
    if (c >= N) return;
    const size_t i = (size_t)b * N + c;
    if (c1[b])      out[i] = p1[i];
    else if (c2[b]) out[i] = p2[i];
    // else: keep p3 already in out
}

extern "C" void kernel_launch(void* const* d_in, const int* in_sizes, int n_in,
                              void* d_out, int out_size, void* d_ws, size_t ws_size,
                              hipStream_t stream)
{
    const float* x   = (const float*)d_in[0];
    const float* W1  = (const float*)d_in[1];
    const float* b1  = (const float*)d_in[2];
    const float* W2  = (const float*)d_in[3];
    const float* b2  = (const float*)d_in[4];
    const float* W3  = (const float*)d_in[5];
    const float* b3  = (const float*)d_in[6];
    const float* H1w = (const float*)d_in[7];
    const float* H1b = (const float*)d_in[8];
    const float* H2w = (const float*)d_in[9];
    const float* H2b = (const float*)d_in[10];
    const float* Fw  = (const float*)d_in[11];
    const float* Fb  = (const float*)d_in[12];
    float* out = (float*)d_out;

    const int B = 8192, D = 2048, H = 2048, C = 1000;

    // workspace carve (~200 MB)
    float* ws = (float*)d_ws;
    float* h1 = ws;                          // B*H  (reused as h3 later)
    float* h2 = h1 + (size_t)B * H;          // B*H
    float* p1 = h2 + (size_t)B * H;          // B*C
    float* p2 = p1 + (size_t)B * C;          // B*C
    int*   c1 = (int*)(p2 + (size_t)B * C);  // B
    int*   c2 = c1 + B;                      // B
    float* h3 = h1;                          // h1 dead after p1 & h2 computed

    dim3 blk(256);
    dim3 gB(H / BN, B / BM);                   // (16, 64) backbone
    dim3 gH((C + BN - 1) / BN, B / BM);        // (8, 64)  heads

    // Stage 1
    gemm_bias_act<<<gB, blk, 0, stream>>>(x,  W1, b1, h1, B, H, D, 1);
    gemm_bias_act<<<gH, blk, 0, stream>>>(h1, H1w, H1b, p1, B, C, H, 0);
    conf_kernel<<<dim3(B), blk, 0, stream>>>(p1, C, c1);
    // Stage 2
    gemm_bias_act<<<gB, blk, 0, stream>>>(h1, W2, b2, h2, B, H, H, 1);
    gemm_bias_act<<<gH, blk, 0, stream>>>(h2, H2w, H2b, p2, B, C, H, 0);
    conf_kernel<<<dim3(B), blk, 0, stream>>>(p2, C, c2);
    // Stage 3 (p3 straight into d_out)
    gemm_bias_act<<<gB, blk, 0, stream>>>(h2, W3, b3, h3, B, H, H, 1);
    gemm_bias_act<<<gH, blk, 0, stream>>>(h3, Fw, Fb, out, B, C, H, 0);
    // First-exit selection
    select_kernel<<<dim3((C + 255) / 256, B), blk, 0, stream>>>(out, p1, p2, c1, c2, C);
}

// Round 2
// 1441.885 us; speedup vs baseline: 2.9439x; 2.9439x over previous
//
#include <hip/hip_runtime.h>
#include <math.h>

typedef __bf16 bf16x8 __attribute__((ext_vector_type(8)));
typedef float f32x4 __attribute__((ext_vector_type(4)));
typedef unsigned short ushort_t;
typedef unsigned int uint_t;

__device__ __forceinline__ ushort_t f2bf(float f) {
    uint_t u = __float_as_uint(f);
    u += 0x7fff + ((u >> 16) & 1);          // RNE (inputs are finite, sane)
    return (ushort_t)(u >> 16);
}
__device__ __forceinline__ float bf2f(ushort_t h) {
    return __uint_as_float(((uint_t)h) << 16);
}

// ---------------- elementwise split: fp32 -> (hi, lo) bf16 ----------------
__global__ __launch_bounds__(256) void split_kernel(
    const float* __restrict__ in, ushort_t* __restrict__ hi,
    ushort_t* __restrict__ lo, long n4)
{
    long i = (long)blockIdx.x * 256 + threadIdx.x;
    if (i >= n4) return;
    float4 v = ((const float4*)in)[i];
    ushort4 h, l;
    h.x = f2bf(v.x); l.x = f2bf(v.x - bf2f(h.x));
    h.y = f2bf(v.y); l.y = f2bf(v.y - bf2f(h.y));
    h.z = f2bf(v.z); l.z = f2bf(v.z - bf2f(h.z));
    h.w = f2bf(v.w); l.w = f2bf(v.w - bf2f(h.w));
    ((ushort4*)hi)[i] = h;
    ((ushort4*)lo)[i] = l;
}

// ------- transpose + split: W [K,N] fp32 row-major -> Wt [Npad,K] bf16 -------
// rows n in [N, Npad) are zero-filled.
__global__ __launch_bounds__(256) void tsplit_kernel(
    const float* __restrict__ W, ushort_t* __restrict__ hi,
    ushort_t* __restrict__ lo, int K, int N, int write_lo)
{
    __shared__ float t[32][33];
    const int tx = threadIdx.x & 31;
    const int ty = threadIdx.x >> 5;          // 0..7
    const int nb = blockIdx.x * 32;           // n tile (over Npad)
    const int kb = blockIdx.y * 32;           // k tile
    #pragma unroll
    for (int i = 0; i < 4; ++i) {
        int k = kb + ty + i * 8;
        int n = nb + tx;
        t[ty + i * 8][tx] = (n < N) ? W[(size_t)k * N + n] : 0.f;
    }
    __syncthreads();
    #pragma unroll
    for (int i = 0; i < 4; ++i) {
        int n = nb + ty + i * 8;              // output row (padded space)
        int k = kb + tx;
        float f = t[tx][ty + i * 8];
        size_t idx = (size_t)n * K + k;
        ushort_t h = f2bf(f);
        hi[idx] = h;
        if (write_lo) lo[idx] = f2bf(f - bf2f(h));
    }
}

// ---------------- MFMA GEMM: C = A @ Bt^T (+bias, +relu) ----------------
// A: [M,K] bf16 (hi[,lo]) row-major. Bt: [Npad,K] bf16 (hi[,lo]) row-major.
// NPASS==3: split-precision (acc += ah*bh + al*bh + ah*bl).
// Output: either Cf (fp32, cols guarded to Ntrue) or Chi[,Clo] (bf16 split).
// M%128==0, Npad = gridDim.x*128, K%32==0.
template <int NPASS>
__global__ __launch_bounds__(256) void gemm_mfma(
    const ushort_t* __restrict__ Ahi, const ushort_t* __restrict__ Alo,
    const ushort_t* __restrict__ Bhi, const ushort_t* __restrict__ Blo,
    const float* __restrict__ bias,
    float* __restrict__ Cf, ushort_t* __restrict__ Chi, ushort_t* __restrict__ Clo,
    int K, int Ntrue, int ldc, int relu_flag)
{
    // LDS chunk layout: chunk c = kb*128 + r covers src row r, k in [kb*8, kb*8+8)
    __shared__ ushort_t As[NPASS == 3 ? 2 : 1][4096];
    __shared__ ushort_t Bs[NPASS == 3 ? 2 : 1][4096];

    const int tid = threadIdx.x;
    const int lane = tid & 63, wave = tid >> 6;
    const int wm = wave >> 1, wn = wave & 1;   // 2x2 waves, 64x64 each
    const int q = lane >> 4, r16 = lane & 15;
    const int m0 = blockIdx.y * 128, n0 = blockIdx.x * 128;

    // staging: chunks c0 = tid (row=tid&127, kb=tid>>7 in {0,1}), c1 = c0+256 (kb+2)
    const int srow = tid & 127;
    const int skb = tid >> 7;
    const size_t ga = (size_t)(m0 + srow) * K + skb * 8;
    const size_t gb = (size_t)(n0 + srow) * K + skb * 8;
    const int ls0 = tid * 8, ls1 = ls0 + 2048;

    f32x4 acc[4][4];
    #pragma unroll
    for (int i = 0; i < 4; ++i)
        #pragma unroll
        for (int j = 0; j < 4; ++j) acc[i][j] = (f32x4)(0.f);

    const int fa = (q * 128 + wm * 64 + r16) * 8;
    const int fb = (q * 128 + wn * 64 + r16) * 8;

    for (int k0 = 0; k0 < K; k0 += 32) {
        uint4 rah0 = *(const uint4*)(Ahi + ga + k0);
        uint4 rah1 = *(const uint4*)(Ahi + ga + k0 + 16);
        uint4 rbh0 = *(const uint4*)(Bhi + gb + k0);
        uint4 rbh1 = *(const uint4*)(Bhi + gb + k0 + 16);
        uint4 ral0, ral1, rbl0, rbl1;
        if (NPASS == 3) {
            ral0 = *(const uint4*)(Alo + ga + k0);
            ral1 = *(const uint4*)(Alo + ga + k0 + 16);
            rbl0 = *(const uint4*)(Blo + gb + k0);
            rbl1 = *(const uint4*)(Blo + gb + k0 + 16);
        }
        __syncthreads();   // prior iteration's frag reads complete
        *(uint4*)(&As[0][ls0]) = rah0;
        *(uint4*)(&As[0][ls1]) = rah1;
        *(uint4*)(&Bs[0][ls0]) = rbh0;
        *(uint4*)(&Bs[0][ls1]) = rbh1;
        if (NPASS == 3) {
            *(uint4*)(&As[NPASS - 2][ls0]) = ral0;
            *(uint4*)(&As[NPASS - 2][ls1]) = ral1;
            *(uint4*)(&Bs[NPASS - 2][ls0]) = rbl0;
            *(uint4*)(&Bs[NPASS - 2][ls1]) = rbl1;
        }
        __syncthreads();   // staging visible

        bf16x8 ah[4], al[4];
        #pragma unroll
        for (int mi = 0; mi < 4; ++mi) {
            ah[mi] = *(const bf16x8*)(&As[0][fa + mi * 128]);
            if (NPASS == 3) al[mi] = *(const bf16x8*)(&As[NPASS - 2][fa + mi * 128]);
        }
        #pragma unroll
        for (int nj = 0; nj < 4; ++nj) {
            bf16x8 bh = *(const bf16x8*)(&Bs[0][fb + nj * 128]);
            bf16x8 bl;
            if (NPASS == 3) bl = *(const bf16x8*)(&Bs[NPASS - 2][fb + nj * 128]);
            #pragma unroll
            for (int mi = 0; mi < 4; ++mi) {
                acc[mi][nj] = __builtin_amdgcn_mfma_f32_16x16x32_bf16(ah[mi], bh, acc[mi][nj], 0, 0, 0);
                if (NPASS == 3) {
                    acc[mi][nj] = __builtin_amdgcn_mfma_f32_16x16x32_bf16(al[mi], bh, acc[mi][nj], 0, 0, 0);
                    acc[mi][nj] = __builtin_amdgcn_mfma_f32_16x16x32_bf16(ah[mi], bl, acc[mi][nj], 0, 0, 0);
                }
            }
        }
    }

    // epilogue: D layout row=(lane>>4)*4+r, col=lane&15 per 16x16 tile
    #pragma unroll
    for (int mi = 0; mi < 4; ++mi) {
        #pragma unroll
        for (int nj = 0; nj < 4; ++nj) {
            const int col = n0 + wn * 64 + nj * 16 + r16;
            const int rowb = m0 + wm * 64 + mi * 16 + q * 4;
            const float bv = (col < Ntrue) ? bias[col] : 0.f;
            #pragma unroll
            for (int r = 0; r < 4; ++r) {
                float v = acc[mi][nj][r] + bv;
                if (relu_flag) v = fmaxf(v, 0.f);
                const size_t idx = (size_t)(rowb + r) * ldc + col;
                if (Cf) {
                    if (col < Ntrue) Cf[idx] = v;
                } else {
                    ushort_t h = f2bf(v);
                    Chi[idx] = h;
                    if (NPASS == 3) Clo[idx] = f2bf(v - bf2f(h));
                }
            }
        }
    }
}

// ---- exit mask: max softmax prob > 0.01  <=>  sum(exp(l - max)) < 100 ----
__global__ __launch_bounds__(256) void conf_kernel(
    const float* __restrict__ P, int N, int* __restrict__ cm)
{
    const int b = blockIdx.x;
    const float* row = P + (size_t)b * N;
    float m = -3.0e38f;
    for (int c = threadIdx.x; c < N; c += 256) m = fmaxf(m, row[c]);
    #pragma unroll
    for (int off = 32; off > 0; off >>= 1) m = fmaxf(m, __shfl_down(m, off));
    __shared__ float red_max[4];
    __shared__ float red_sum[4];
    const int wave = threadIdx.x >> 6;
    const int lane = threadIdx.x & 63;
    if (lane == 0) red_max[wave] = m;
    __syncthreads();
    m = fmaxf(fmaxf(red_max[0], red_max[1]), fmaxf(red_max[2], red_max[3]));
    float s = 0.f;
    for (int c = threadIdx.x; c < N; c += 256) s += expf(row[c] - m);
    #pragma unroll
    for (int off = 32; off > 0; off >>= 1) s += __shfl_down(s, off);
    if (lane == 0) red_sum[wave] = s;
    __syncthreads();
    if (threadIdx.x == 0) {
        float tot = red_sum[0] + red_sum[1] + red_sum[2] + red_sum[3];
        cm[b] = (tot < 100.0f) ? 1 : 0;
    }
}

// out currently holds p1; rows that didn't exit at stage 1 get p2 or p3.
__global__ __launch_bounds__(256) void select_kernel(
    float* __restrict__ out, const float* __restrict__ p2,
    const float* __restrict__ p3, const int* __restrict__ c1,
    const int* __restrict__ c2, int N)
{
    const int b = blockIdx.y;
    if (c1[b]) return;
    const int c = blockIdx.x * 256 + threadIdx.x;
    if (c >= N) return;
    const size_t i = (size_t)b * N + c;
    out[i] = c2[b] ? p2[i] : p3[i];
}

extern "C" void kernel_launch(void* const* d_in, const int* in_sizes, int n_in,
                              void* d_out, int out_size, void* d_ws, size_t ws_size,
                              hipStream_t stream)
{
    const float* x   = (const float*)d_in[0];
    const float* W1  = (const float*)d_in[1];
    const float* b1  = (const float*)d_in[2];
    const float* W2  = (const float*)d_in[3];
    const float* b2  = (const float*)d_in[4];
    const float* W3  = (const float*)d_in[5];
    const float* b3  = (const float*)d_in[6];
    const float* H1w = (const float*)d_in[7];
    const float* H1b = (const float*)d_in[8];
    const float* H2w = (const float*)d_in[9];
    const float* H2b = (const float*)d_in[10];
    const float* Fw  = (const float*)d_in[11];
    const float* Fb  = (const float*)d_in[12];
    float* out = (float*)d_out;

    const int B = 8192, D = 2048, Hh = 2048, Cc = 1000, Cpad = 1024;

    // ---- workspace carve (~192 MB; ushort units) ----
    ushort_t* xhi  = (ushort_t*)d_ws;             // B*D   (reused: h2hi, then p3)
    ushort_t* xlo  = xhi + (size_t)B * D;         // B*D   (reused: h2lo)
    ushort_t* h1hi = xlo + (size_t)B * D;         // B*H   (reused: h3hi)
    ushort_t* h1lo = h1hi + (size_t)B * Hh;       // B*H
    ushort_t* W0hi = h1lo + (size_t)B * Hh;       // 2048*2048 (W1t/W2t/W3t)
    ushort_t* W0lo = W0hi + (size_t)Hh * Hh;
    ushort_t* W1thi = W0lo + (size_t)Hh * Hh;     // 1024*2048 (H1wt/H2wt/Fwt)
    ushort_t* W1tlo = W1thi + (size_t)Cpad * Hh;
    float* p2 = (float*)(W1tlo + (size_t)Cpad * Hh);  // B*Cc fp32
    int* c1 = (int*)(p2 + (size_t)B * Cc);
    int* c2 = c1 + B;
    float* p3 = (float*)xhi;                      // reuse after h2 dead

    ushort_t* h2hi = xhi;  ushort_t* h2lo = xlo;
    ushort_t* h3hi = h1hi;

    dim3 blk(256);
    const dim3 gBB(16, 64);   // backbone GEMM grid (2048/128, 8192/128)
    const dim3 gHD(8, 64);    // head GEMM grid (1024/128, 64)
    const dim3 gT2(64, 64);   // tsplit 2048x2048
    const dim3 gTH(32, 64);   // tsplit head (Npad=1024, K=2048)

    // Stage 1
    split_kernel<<<(B * D / 4 + 255) / 256, blk, 0, stream>>>(x, xhi, xlo, (long)B * D / 4);
    tsplit_kernel<<<gT2, blk, 0, stream>>>(W1, W0hi, W0lo, D, Hh, 1);
    gemm_mfma<3><<<gBB, blk, 0, stream>>>(xhi, xlo, W0hi, W0lo, b1,
                                          nullptr, h1hi, h1lo, D, Hh, Hh, 1);
    tsplit_kernel<<<gTH, blk, 0, stream>>>(H1w, W1thi, W1tlo, Hh, Cc, 1);
    gemm_mfma<3><<<gHD, blk, 0, stream>>>(h1hi, h1lo, W1thi, W1tlo, H1b,
                                          out, nullptr, nullptr, Hh, Cc, Cc, 0);
    conf_kernel<<<dim3(B), blk, 0, stream>>>(out, Cc, c1);

    // Stage 2
    tsplit_kernel<<<gT2, blk, 0, stream>>>(W2, W0hi, W0lo, Hh, Hh, 1);
    gemm_mfma<3><<<gBB, blk, 0, stream>>>(h1hi, h1lo, W0hi, W0lo, b2,
                                          nullptr, h2hi, h2lo, Hh, Hh, Hh, 1);
    tsplit_kernel<<<gTH, blk, 0, stream>>>(H2w, W1thi, W1tlo, Hh, Cc, 1);
    gemm_mfma<3><<<gHD, blk, 0, stream>>>(h2hi, h2lo, W1thi, W1tlo, H2b,
                                          p2, nullptr, nullptr, Hh, Cc, Cc, 0);
    conf_kernel<<<dim3(B), blk, 0, stream>>>(p2, Cc, c2);

    // Stage 3 (plain bf16, single pass — only needs 0.074 output accuracy)
    tsplit_kernel<<<gT2, blk, 0, stream>>>(W3, W0hi, nullptr, Hh, Hh, 0);
    gemm_mfma<1><<<gBB, blk, 0, stream>>>(h2hi, nullptr, W0hi, nullptr, b3,
                                          nullptr, h3hi, nullptr, Hh, Hh, Hh, 1);
    tsplit_kernel<<<gTH, blk, 0, stream>>>(Fw, W1thi, nullptr, Hh, Cc, 0);
    gemm_mfma<1><<<gHD, blk, 0, stream>>>(h3hi, nullptr, W1thi, nullptr, Fb,
                                          p3, nullptr, nullptr, Hh, Cc, Cc, 0);

    // First-exit selection (out already holds p1)
    select_kernel<<<dim3((Cc + 255) / 256, B), blk, 0, stream>>>(out, p2, p3, c1, c2, Cc);
}

// Round 3
// 1396.567 us; speedup vs baseline: 3.0394x; 1.0324x over previous
//
#include <hip/hip_runtime.h>
#include <math.h>

typedef __bf16 bf16x8 __attribute__((ext_vector_type(8)));
typedef float f32x4 __attribute__((ext_vector_type(4)));
typedef unsigned short ushort_t;
typedef unsigned int uint_t;

__device__ __forceinline__ ushort_t f2bf(float f) {
    uint_t u = __float_as_uint(f);
    u += 0x7fff + ((u >> 16) & 1);          // RNE
    return (ushort_t)(u >> 16);
}
__device__ __forceinline__ float bf2f(ushort_t h) {
    return __uint_as_float(((uint_t)h) << 16);
}

// async global->LDS, 16B per lane. LDS dest is wave-uniform base + lane*16.
__device__ __forceinline__ void ll16(const ushort_t* g, ushort_t* l) {
    __builtin_amdgcn_global_load_lds(
        (const __attribute__((address_space(1))) unsigned int*)g,
        (__attribute__((address_space(3))) unsigned int*)l, 16, 0, 0);
}

// ---------------- elementwise split: fp32 -> (hi, lo) bf16 ----------------
__global__ __launch_bounds__(256) void split_kernel(
    const float* __restrict__ in, ushort_t* __restrict__ hi,
    ushort_t* __restrict__ lo, long n4)
{
    long i = (long)blockIdx.x * 256 + threadIdx.x;
    if (i >= n4) return;
    float4 v = ((const float4*)in)[i];
    ushort4 h, l;
    h.x = f2bf(v.x); l.x = f2bf(v.x - bf2f(h.x));
    h.y = f2bf(v.y); l.y = f2bf(v.y - bf2f(h.y));
    h.z = f2bf(v.z); l.z = f2bf(v.z - bf2f(h.z));
    h.w = f2bf(v.w); l.w = f2bf(v.w - bf2f(h.w));
    ((ushort4*)hi)[i] = h;
    ((ushort4*)lo)[i] = l;
}

// ------- transpose + split: W [K,N] fp32 row-major -> Wt [Npad,K] bf16 -------
__global__ __launch_bounds__(256) void tsplit_kernel(
    const float* __restrict__ W, ushort_t* __restrict__ hi,
    ushort_t* __restrict__ lo, int K, int N, int write_lo)
{
    __shared__ float t[32][33];
    const int tx = threadIdx.x & 31;
    const int ty = threadIdx.x >> 5;
    const int nb = blockIdx.x * 32;
    const int kb = blockIdx.y * 32;
    #pragma unroll
    for (int i = 0; i < 4; ++i) {
        int k = kb + ty + i * 8;
        int n = nb + tx;
        t[ty + i * 8][tx] = (n < N) ? W[(size_t)k * N + n] : 0.f;
    }
    __syncthreads();
    #pragma unroll
    for (int i = 0; i < 4; ++i) {
        int n = nb + ty + i * 8;
        int k = kb + tx;
        float f = t[tx][ty + i * 8];
        size_t idx = (size_t)n * K + k;
        ushort_t h = f2bf(f);
        hi[idx] = h;
        if (write_lo) lo[idx] = f2bf(f - bf2f(h));
    }
}

// ---------------- MFMA GEMM: C = A @ Bt^T (+bias, +relu) ----------------
// A: [M,K] bf16 (hi[,lo]); Bt: [Npad,K] bf16 (hi[,lo]).  NPASS==3: split fp32-ish.
// Optional dynamic M (cntp) and row indirection (rowidx) for compacted stages.
// Staging via global_load_lds (m97 2-barrier structure).
template <int NPASS>
__global__ __launch_bounds__(256) void gemm_mfma(
    const ushort_t* __restrict__ Ahi, const ushort_t* __restrict__ Alo,
    const ushort_t* __restrict__ Bhi, const ushort_t* __restrict__ Blo,
    const float* __restrict__ bias,
    float* __restrict__ Cf, ushort_t* __restrict__ Chi, ushort_t* __restrict__ Clo,
    int K, int Ntrue, int ldc, int relu_flag,
    const int* __restrict__ rowidx, const int* __restrict__ cntp, int Mfull)
{
    __shared__ __align__(16) ushort_t As[NPASS == 3 ? 2 : 1][4096];
    __shared__ __align__(16) ushort_t Bs[NPASS == 3 ? 2 : 1][4096];

    const int tid = threadIdx.x;
    const int m0 = blockIdx.y * 128, n0 = blockIdx.x * 128;
    int Meff = Mfull;
    if (cntp) Meff = *cntp;
    if (m0 >= ((Meff + 127) & ~127)) return;   // block-uniform early exit

    const int lane = tid & 63, wave = tid >> 6;
    const int wm = wave >> 1, wn = wave & 1;   // 2x2 waves, 64x64 each
    const int q = lane >> 4, r16 = lane & 15;

    // staging chunk = tid: row = tid&127, kb = tid>>7; LDS offset tid*16B
    const int srow = tid & 127;
    const int skb = tid >> 7;
    int arow = m0 + srow;
    if (rowidx) arow = rowidx[(arow < Meff) ? arow : (Meff - 1)];
    const size_t ga = (size_t)arow * K + skb * 8;
    const size_t gb = (size_t)(n0 + srow) * K + skb * 8;

    // wave-uniform LDS bases (HW adds lane*16B); +2048 ushorts for chunk 2
    ushort_t* const a0 = &As[0][wave * 512];
    ushort_t* const b0 = &Bs[0][wave * 512];
    ushort_t* const a1 = &As[NPASS == 3 ? 1 : 0][wave * 512];
    ushort_t* const b1 = &Bs[NPASS == 3 ? 1 : 0][wave * 512];

    f32x4 acc[4][4];
    #pragma unroll
    for (int i = 0; i < 4; ++i)
        #pragma unroll
        for (int j = 0; j < 4; ++j) acc[i][j] = (f32x4)(0.f);

    const int fa = (q * 128 + wm * 64 + r16) * 8;
    const int fb = (q * 128 + wn * 64 + r16) * 8;

    for (int k0 = 0; k0 < K; k0 += 32) {
        __syncthreads();   // prior iteration's frag reads complete
        ll16(Ahi + ga + k0,      a0);
        ll16(Ahi + ga + k0 + 16, a0 + 2048);
        ll16(Bhi + gb + k0,      b0);
        ll16(Bhi + gb + k0 + 16, b0 + 2048);
        if (NPASS == 3) {
            ll16(Alo + ga + k0,      a1);
            ll16(Alo + ga + k0 + 16, a1 + 2048);
            ll16(Blo + gb + k0,      b1);
            ll16(Blo + gb + k0 + 16, b1 + 2048);
        }
        __syncthreads();   // vmcnt(0) drain + barrier: staging visible

        bf16x8 ah[4], al[4];
        #pragma unroll
        for (int mi = 0; mi < 4; ++mi) {
            ah[mi] = *(const bf16x8*)(&As[0][fa + mi * 128]);
            if (NPASS == 3) al[mi] = *(const bf16x8*)(&As[NPASS - 2][fa + mi * 128]);
        }
        #pragma unroll
        for (int nj = 0; nj < 4; ++nj) {
            bf16x8 bh = *(const bf16x8*)(&Bs[0][fb + nj * 128]);
            bf16x8 bl;
            if (NPASS == 3) bl = *(const bf16x8*)(&Bs[NPASS - 2][fb + nj * 128]);
            #pragma unroll
            for (int mi = 0; mi < 4; ++mi) {
                acc[mi][nj] = __builtin_amdgcn_mfma_f32_16x16x32_bf16(ah[mi], bh, acc[mi][nj], 0, 0, 0);
                if (NPASS == 3) {
                    acc[mi][nj] = __builtin_amdgcn_mfma_f32_16x16x32_bf16(al[mi], bh, acc[mi][nj], 0, 0, 0);
                    acc[mi][nj] = __builtin_amdgcn_mfma_f32_16x16x32_bf16(ah[mi], bl, acc[mi][nj], 0, 0, 0);
                }
            }
        }
    }

    #pragma unroll
    for (int mi = 0; mi < 4; ++mi) {
        #pragma unroll
        for (int nj = 0; nj < 4; ++nj) {
            const int col = n0 + wn * 64 + nj * 16 + r16;
            const int rowb = m0 + wm * 64 + mi * 16 + q * 4;
            const float bv = (col < Ntrue) ? bias[col] : 0.f;
            #pragma unroll
            for (int r = 0; r < 4; ++r) {
                float v = acc[mi][nj][r] + bv;
                if (relu_flag) v = fmaxf(v, 0.f);
                const size_t idx = (size_t)(rowb + r) * ldc + col;
                if (Cf) {
                    if (col < Ntrue) Cf[idx] = v;
                } else {
                    ushort_t h = f2bf(v);
                    Chi[idx] = h;
                    if (NPASS == 3) Clo[idx] = f2bf(v - bf2f(h));
                }
            }
        }
    }
}

// ---- exit mask: max softmax prob > 0.01  <=>  sum(exp(l - max)) < 100 ----
__global__ __launch_bounds__(256) void conf_kernel(
    const float* __restrict__ P, int N, int* __restrict__ cm,
    const int* __restrict__ cntp)
{
    const int b = blockIdx.x;
    if (cntp && b >= *cntp) return;
    const float* row = P + (size_t)b * N;
    float m = -3.0e38f;
    for (int c = threadIdx.x; c < N; c += 256) m = fmaxf(m, row[c]);
    #pragma unroll
    for (int off = 32; off > 0; off >>= 1) m = fmaxf(m, __shfl_down(m, off));
    __shared__ float red_max[4];
    __shared__ float red_sum[4];
    const int wave = threadIdx.x >> 6;
    const int lane = threadIdx.x & 63;
    if (lane == 0) red_max[wave] = m;
    __syncthreads();
    m = fmaxf(fmaxf(red_max[0], red_max[1]), fmaxf(red_max[2], red_max[3]));
    float s = 0.f;
    for (int c = threadIdx.x; c < N; c += 256) s += expf(row[c] - m);
    #pragma unroll
    for (int off = 32; off > 0; off >>= 1) s += __shfl_down(s, off);
    if (lane == 0) red_sum[wave] = s;
    __syncthreads();
    if (threadIdx.x == 0) {
        float tot = red_sum[0] + red_sum[1] + red_sum[2] + red_sum[3];
        cm[b] = (tot < 100.0f) ? 1 : 0;
    }
}

__global__ void init_kernel(int* cnt1, int* cnt2) {
    if (threadIdx.x == 0) { *cnt1 = 0; *cnt2 = 0; }
}

// compact: positions i < nlim with mask[i]==0 -> idx[atomic slot]
__global__ __launch_bounds__(256) void build_kernel(
    const int* __restrict__ mask, int n, const int* __restrict__ nlimp,
    int* __restrict__ cnt, int* __restrict__ idx)
{
    int i = blockIdx.x * 256 + threadIdx.x;
    int nl = nlimp ? *nlimp : n;
    if (i >= nl) return;
    if (!mask[i]) { int p = atomicAdd(cnt, 1); idx[p] = i; }
}

// out[idx1[j]] = p2[j]  where j survived stage1 but exited at stage2
__global__ __launch_bounds__(256) void scatter2_kernel(
    float* __restrict__ out, const float* __restrict__ p2,
    const int* __restrict__ idx1, const int* __restrict__ c2m,
    const int* __restrict__ cntp, int N)
{
    const int j = blockIdx.y;
    if (j >= *cntp || !c2m[j]) return;
    const int c = blockIdx.x * 256 + threadIdx.x;
    if (c >= N) return;
    out[(size_t)idx1[j] * N + c] = p2[(size_t)j * N + c];
}

// out[idx1[idx2[jj]]] = p3[jj]  for rows that reached stage 3
__global__ __launch_bounds__(256) void scatter3_kernel(
    float* __restrict__ out, const float* __restrict__ p3,
    const int* __restrict__ idx1, const int* __restrict__ idx2,
    const int* __restrict__ cntp, int N)
{
    const int jj = blockIdx.y;
    if (jj >= *cntp) return;
    const int c = blockIdx.x * 256 + threadIdx.x;
    if (c >= N) return;
    out[(size_t)idx1[idx2[jj]] * N + c] = p3[(size_t)jj * N + c];
}

extern "C" void kernel_launch(void* const* d_in, const int* in_sizes, int n_in,
                              void* d_out, int out_size, void* d_ws, size_t ws_size,
                              hipStream_t stream)
{
    const float* x   = (const float*)d_in[0];
    const float* W1  = (const float*)d_in[1];
    const float* b1  = (const float*)d_in[2];
    const float* W2  = (const float*)d_in[3];
    const float* b2  = (const float*)d_in[4];
    const float* W3  = (const float*)d_in[5];
    const float* b3  = (const float*)d_in[6];
    const float* H1w = (const float*)d_in[7];
    const float* H1b = (const float*)d_in[8];
    const float* H2w = (const float*)d_in[9];
    const float* H2b = (const float*)d_in[10];
    const float* Fw  = (const float*)d_in[11];
    const float* Fb  = (const float*)d_in[12];
    float* out = (float*)d_out;

    const int B = 8192, D = 2048, Hh = 2048, Cc = 1000;

    // ---- workspace carve (~192 MB; ushort units) ----
    ushort_t* xhi  = (ushort_t*)d_ws;             // B*D  (reused: h2hi compact)
    ushort_t* xlo  = xhi + (size_t)B * D;         // B*D  (reused: h2lo compact)
    ushort_t* h1hi = xlo + (size_t)B * D;         // B*H  (reused: h3hi compact)
    ushort_t* h1lo = h1hi + (size_t)B * Hh;       // B*H  (reused: p3 compact fp32)
    ushort_t* W0hi = h1lo + (size_t)B * Hh;       // 2048x2048 (W1t/W2t/W3t)
    ushort_t* W0lo = W0hi + (size_t)Hh * Hh;
    ushort_t* W1thi = W0lo + (size_t)Hh * Hh;     // 1024x2048 (heads)
    ushort_t* W1tlo = W1thi + (size_t)1024 * Hh;
    float* p2 = (float*)(W1tlo + (size_t)1024 * Hh);  // B*Cc fp32 (compact)
    int* c1   = (int*)(p2 + (size_t)B * Cc);      // B  dense stage-1 mask
    int* c2m  = c1 + B;                           // B  stage-2 mask (compact space)
    int* idx1 = c2m + B;                          // B
    int* idx2 = idx1 + B;                         // B
    int* cnt1 = idx2 + B;
    int* cnt2 = cnt1 + 1;

    ushort_t* h2hi = xhi;  ushort_t* h2lo = xlo;
    ushort_t* h3hi = h1hi;
    float* p3 = (float*)h1lo;

    dim3 blk(256);
    const dim3 gBB(16, 64);   // backbone GEMM (2048/128, 8192/128)
    const dim3 gHD(8, 64);    // head GEMM (1024/128, 64)
    const dim3 gT2(64, 64);   // tsplit 2048x2048
    const dim3 gTH(32, 64);   // tsplit head

    init_kernel<<<1, 64, 0, stream>>>(cnt1, cnt2);

    // Stage 1 (dense)
    split_kernel<<<(B * D / 4 + 255) / 256, blk, 0, stream>>>(x, xhi, xlo, (long)B * D / 4);
    tsplit_kernel<<<gT2, blk, 0, stream>>>(W1, W0hi, W0lo, D, Hh, 1);
    gemm_mfma<3><<<gBB, blk, 0, stream>>>(xhi, xlo, W0hi, W0lo, b1,
                                          nullptr, h1hi, h1lo, D, Hh, Hh, 1,
                                          nullptr, nullptr, B);
    tsplit_kernel<<<gTH, blk, 0, stream>>>(H1w, W1thi, W1tlo, Hh, Cc, 1);
    gemm_mfma<3><<<gHD, blk, 0, stream>>>(h1hi, h1lo, W1thi, W1tlo, H1b,
                                          out, nullptr, nullptr, Hh, Cc, Cc, 0,
                                          nullptr, nullptr, B);
    conf_kernel<<<dim3(B), blk, 0, stream>>>(out, Cc, c1, nullptr);
    build_kernel<<<dim3(B / 256), blk, 0, stream>>>(c1, B, nullptr, cnt1, idx1);

    // Stage 2 (compacted to !c1 rows)
    tsplit_kernel<<<gT2, blk, 0, stream>>>(W2, W0hi, W0lo, Hh, Hh, 1);
    gemm_mfma<3><<<gBB, blk, 0, stream>>>(h1hi, h1lo, W0hi, W0lo, b2,
                                          nullptr, h2hi, h2lo, Hh, Hh, Hh, 1,
                                          idx1, cnt1, B);
    tsplit_kernel<<<gTH, blk, 0, stream>>>(H2w, W1thi, W1tlo, Hh, Cc, 1);
    gemm_mfma<3><<<gHD, blk, 0, stream>>>(h2hi, h2lo, W1thi, W1tlo, H2b,
                                          p2, nullptr, nullptr, Hh, Cc, Cc, 0,
                                          nullptr, cnt1, B);
    conf_kernel<<<dim3(B), blk, 0, stream>>>(p2, Cc, c2m, cnt1);
    build_kernel<<<dim3(B / 256), blk, 0, stream>>>(c2m, B, cnt1, cnt2, idx2);

    // Stage 3 (compacted to !c1 && !c2 rows; plain bf16 single pass)
    tsplit_kernel<<<gT2, blk, 0, stream>>>(W3, W0hi, nullptr, Hh, Hh, 0);
    gemm_mfma<1><<<gBB, blk, 0, stream>>>(h2hi, nullptr, W0hi, nullptr, b3,
                                          nullptr, h3hi, nullptr, Hh, Hh, Hh, 1,
                                          idx2, cnt2, B);
    tsplit_kernel<<<gTH, blk, 0, stream>>>(Fw, W1thi, nullptr, Hh, Cc, 0);
    gemm_mfma<1><<<gHD, blk, 0, stream>>>(h3hi, nullptr, W1thi, nullptr, Fb,
                                          p3, nullptr, nullptr, Hh, Cc, Cc, 0,
                                          nullptr, cnt2, B);

    // Merge: out holds p1; overwrite stage-2 exits then stage-3 rows
    scatter2_kernel<<<dim3((Cc + 255) / 256, B), blk, 0, stream>>>(out, p2, idx1, c2m, cnt1, Cc);
    scatter3_kernel<<<dim3((Cc + 255) / 256, B), blk, 0, stream>>>(out, p3, idx1, idx2, cnt2, Cc);
}